// Round 2
// baseline (621.626 us; speedup 1.0000x reference)
//
#include <hip/hip_runtime.h>
#include <cstddef>

#define BB    16
#define NN    2048
#define BN    (BB * NN)
#define EPSF  1e-9f
#define TPB   256
#define CPT   4                 // columns/rows per thread
#define SPLIT 16                // reduction-dim split (occupancy)
#define TILE  (NN / SPLIT)      // 128 staged rows/cols per block

// exp2f lowers to v_exp_f32 under -O3 on gfx950 (no libcall in the hot loop).
__device__ __forceinline__ float fast_exp2(float x) { return exp2f(x); }

// ---------------- init: cost=cur=1, zero accumulators ----------------
__global__ void init_k(float* __restrict__ cost, float* __restrict__ cur,
                       float* __restrict__ S, float* __restrict__ T,
                       float* __restrict__ RS, float* __restrict__ RR) {
    int i = blockIdx.x * TPB + threadIdx.x;
    cost[i] = 1.0f; cur[i] = 1.0f;
    S[i] = 0.0f; T[i] = 0.0f; RS[i] = 0.0f; RR[i] = 0.0f;
}

// ---------------- pass A: column sums S[m]=sum_n e, T[m]=sum_n e*cur[n] ----
// grid = BB * 2 * SPLIT blocks of 256 threads; each thread owns 4 columns,
// block reduces over a 128-row slice (partials via atomicAdd).
__global__ __launch_bounds__(TPB) void passA(const float* __restrict__ preds,
                                             const float* __restrict__ labels,
                                             const float* __restrict__ cur,
                                             float* __restrict__ S,
                                             float* __restrict__ T,
                                             float c1 /* ef*log2e */) {
    __shared__ float s_px[TILE], s_py[TILE], s_pz[TILE], s_q[TILE], s_cu[TILE];
    int blk   = blockIdx.x;
    int split = blk % SPLIT;
    int mc    = (blk / SPLIT) & 1;
    int b     = blk / (SPLIT * 2);
    int t     = threadIdx.x;

    int r0 = split * TILE;
    if (t < TILE) {
        int r = r0 + t;
        const float* p = preds + ((size_t)b * NN + r) * 3;
        float px = p[0], py = p[1], pz = p[2];
        s_px[t] = px; s_py[t] = py; s_pz[t] = pz;
        s_q[t]  = c1 * (px * px + py * py + pz * pz);   // c1*|p|^2
        s_cu[t] = cur[b * NN + r];
    }
    __syncthreads();

    int m0 = mc * (TPB * CPT) + t;
    float gx[CPT], gy[CPT], gz[CPT], am[CPT], Sa[CPT], Ta[CPT];
    float n2c1 = -2.0f * c1;
#pragma unroll
    for (int c = 0; c < CPT; c++) {
        int m = m0 + c * TPB;
        const float* l = labels + ((size_t)b * NN + m) * 3;
        float lx = l[0], ly = l[1], lz = l[2];
        gx[c] = n2c1 * lx; gy[c] = n2c1 * ly; gz[c] = n2c1 * lz;
        am[c] = c1 * (lx * lx + ly * ly + lz * lz);     // c1*|l|^2
        Sa[c] = 0.0f; Ta[c] = 0.0f;
    }

    for (int j = 0; j < TILE; j++) {
        float px = s_px[j], py = s_py[j], pz = s_pz[j];
        float q = s_q[j], cu = s_cu[j];
#pragma unroll
        for (int c = 0; c < CPT; c++) {
            // arg = log2e*ef*pw  (pw = |p|^2+|l|^2-2 p.l)
            float arg = fmaf(px, gx[c], fmaf(py, gy[c], fmaf(pz, gz[c], q + am[c])));
            float e = fast_exp2(arg);
            Sa[c] += e;
            Ta[c] = fmaf(e, cu, Ta[c]);
        }
    }
#pragma unroll
    for (int c = 0; c < CPT; c++) {
        int m = m0 + c * TPB;
        atomicAdd(&S[b * NN + m], Sa[c]);
        atomicAdd(&T[b * NN + m], Ta[c]);
    }
}

// ---------------- combine A: per-column scalars, cc + cost update --------
__global__ void combA(float* __restrict__ cost, float* __restrict__ cc,
                      float* __restrict__ S, float* __restrict__ T) {
    int i = blockIdx.x * TPB + threadIdx.x;
    float co = cost[i], s = S[i], tt = T[i];
    float D1 = fmaf(co, s, EPSF);                 // sum(bids)+eps
    float S2 = co * tt / D1;                      // sum(bids2)
    float bw = fminf(co / (S2 + EPSF), 1.0f);     // bid_wt
    cc[i] = co * bw / D1;
    cost[i] = fmaxf(fmaf(-S2, bw, co), 0.0f);
    S[i] = 0.0f; T[i] = 0.0f;                     // reset for next round
}

// ---------------- pass B: row sums rs[n]=sum_m e*cc, rr[n]=sum_m e*cc*pw --
__global__ __launch_bounds__(TPB) void passB(const float* __restrict__ preds,
                                             const float* __restrict__ labels,
                                             const float* __restrict__ cc,
                                             float* __restrict__ RS,
                                             float* __restrict__ RR,
                                             float c1) {
    __shared__ float s_lx[TILE], s_ly[TILE], s_lz[TILE], s_lm[TILE], s_cc[TILE];
    int blk   = blockIdx.x;
    int split = blk % SPLIT;          // m-slice
    int nc    = (blk / SPLIT) & 1;    // row chunk
    int b     = blk / (SPLIT * 2);
    int t     = threadIdx.x;

    int m0 = split * TILE;
    if (t < TILE) {
        int m = m0 + t;
        const float* l = labels + ((size_t)b * NN + m) * 3;
        float lx = l[0], ly = l[1], lz = l[2];
        s_lx[t] = lx; s_ly[t] = ly; s_lz[t] = lz;
        s_lm[t] = lx * lx + ly * ly + lz * lz;     // raw |l|^2 (need pw itself)
        s_cc[t] = cc[b * NN + m];
    }
    __syncthreads();

    int n0 = nc * (TPB * CPT) + t;
    float px[CPT], py[CPT], pz[CPT], pn[CPT], RSa[CPT], RRa[CPT];
#pragma unroll
    for (int c = 0; c < CPT; c++) {
        int n = n0 + c * TPB;
        const float* p = preds + ((size_t)b * NN + n) * 3;
        px[c] = p[0]; py[c] = p[1]; pz[c] = p[2];
        pn[c] = px[c] * px[c] + py[c] * py[c] + pz[c] * pz[c];
        RSa[c] = 0.0f; RRa[c] = 0.0f;
    }

    for (int j = 0; j < TILE; j++) {
        float lx = s_lx[j], ly = s_ly[j], lz = s_lz[j];
        float lm2 = s_lm[j], ccm = s_cc[j];
#pragma unroll
        for (int c = 0; c < CPT; c++) {
            float dot = fmaf(px[c], lx, fmaf(py[c], ly, pz[c] * lz));
            float pw  = fmaf(-2.0f, dot, pn[c] + lm2);
            float e   = fast_exp2(c1 * pw);
            float w   = e * ccm;
            RSa[c] += w;
            RRa[c] = fmaf(w, pw, RRa[c]);
        }
    }
#pragma unroll
    for (int c = 0; c < CPT; c++) {
        int n = n0 + c * TPB;
        atomicAdd(&RS[b * NN + n], RSa[c]);
        atomicAdd(&RR[b * NN + n], RRa[c]);
    }
}

// ---------------- combine B: currency update + result accumulation -------
__global__ void combB(float* __restrict__ cur, float* __restrict__ RS,
                      float* __restrict__ RR, float* __restrict__ out) {
    int i = blockIdx.x * TPB + threadIdx.x;
    float cu = cur[i], rs = RS[i], rr = RR[i];
    float contrib = cu * rr;                       // sum_m bids3*pw for row
    cur[i] = fmaxf(cu * (1.0f - rs), 0.0f);        // cu - cu*rs
    RS[i] = 0.0f; RR[i] = 0.0f;

    // block-reduce contrib -> one atomic per block
#pragma unroll
    for (int o = 32; o > 0; o >>= 1)
        contrib += __shfl_down(contrib, o, 64);
    __shared__ float wsum[TPB / 64];
    if ((threadIdx.x & 63) == 0) wsum[threadIdx.x >> 6] = contrib;
    __syncthreads();
    if (threadIdx.x == 0) {
        float s = 0.0f;
#pragma unroll
        for (int w = 0; w < TPB / 64; w++) s += wsum[w];
        atomicAdd(out, s);
    }
}

extern "C" void kernel_launch(void* const* d_in, const int* in_sizes, int n_in,
                              void* d_out, int out_size, void* d_ws, size_t ws_size,
                              hipStream_t stream) {
    const float* preds  = (const float*)d_in[0];
    const float* labels = (const float*)d_in[1];
    float* out = (float*)d_out;
    float* ws  = (float*)d_ws;

    float* cost = ws + 0 * BN;
    float* cur  = ws + 1 * BN;
    float* cc   = ws + 2 * BN;
    float* S    = ws + 3 * BN;
    float* T    = ws + 4 * BN;
    float* RS   = ws + 5 * BN;
    float* RR   = ws + 6 * BN;   // total ws use: 7*BN*4 = 896 KB

    hipMemsetAsync(d_out, 0, sizeof(float), stream);
    init_k<<<BN / TPB, TPB, 0, stream>>>(cost, cur, S, T, RS, RR);

    static const float efs[10] = {-16384.0f, -4096.0f, -1024.0f, -256.0f, -64.0f,
                                  -16.0f, -4.0f, -1.0f, -0.25f, 0.0f};
    const float log2e = 1.44269504088896f;
    int pgrid = BB * 2 * SPLIT;   // 512 blocks
    for (int s = 0; s < 10; s++) {
        float c1 = efs[s] * log2e;
        passA<<<pgrid, TPB, 0, stream>>>(preds, labels, cur, S, T, c1);
        combA<<<BN / TPB, TPB, 0, stream>>>(cost, cc, S, T);
        passB<<<pgrid, TPB, 0, stream>>>(preds, labels, cc, RS, RR, c1);
        combB<<<BN / TPB, TPB, 0, stream>>>(cur, RS, RR, out);
    }
}

// Round 3
// 351.629 us; speedup vs baseline: 1.7678x; 1.7678x over previous
//
#include <hip/hip_runtime.h>
#include <cstddef>

#define BB    16
#define NN    2048
#define BN    (BB * NN)
#define EPSF  1e-9f
#define TPB   512
#define CPT   2                 // columns/rows per thread
#define SPLIT 16                // reduction-dim split
#define TILE  128               // NN/SPLIT rows (or cols) staged per block
#define CHUNK 1024              // TPB*CPT columns (rows) per block

// OCML native exp2 is always linkable; builtin preferred (both -> v_exp_f32).
extern "C" __device__ float __ocml_native_exp2_f32(float);
__device__ __forceinline__ float fast_exp2(float x) {
#if __has_builtin(__builtin_amdgcn_exp2f)
    return __builtin_amdgcn_exp2f(x);
#else
    return __ocml_native_exp2_f32(x);
#endif
}

// passA (fused with prev round's combB):
//   prologue: cur_k = max(cur_{k-1}*(1-RS_{k-1}),0); out += sum cur_{k-1}*RR_{k-1};
//             zero RS/RR[k&1] for this round's passB; write cur_k (mc==0 blocks).
//   main:     S[m] += sum_n e, T[m] += sum_n e*cur_k[n]   (atomic partials)
__global__ __launch_bounds__(TPB, 4) void passA(
    const float* __restrict__ preds, const float* __restrict__ labels,
    const float* __restrict__ curprev, float* __restrict__ curout,
    const float* __restrict__ RSprev, const float* __restrict__ RRprev,
    float* __restrict__ RSz, float* __restrict__ RRz,
    float* __restrict__ Sacc, float* __restrict__ Tacc,
    float* __restrict__ out, float c1, int k)
{
    __shared__ float4 s_p[TILE];   // (px,py,pz, c1*|p|^2)
    __shared__ float  s_cu[TILE];
    __shared__ float  s_red[2];
    int blk = blockIdx.x;
    int split = blk & 15, mc = (blk >> 4) & 1, b = blk >> 5;
    int t = threadIdx.x;
    int base = b * NN;

    if (t < TILE) {
        int idx = base + split * TILE + t;
        const float* p = preds + (size_t)idx * 3;
        float px = p[0], py = p[1], pz = p[2];
        float pn = px * px + py * py + pz * pz;
        float cu, contrib = 0.0f;
        if (k == 0) cu = 1.0f;
        else {
            float cup = curprev[idx], rs = RSprev[idx], rr = RRprev[idx];
            contrib = cup * rr;                       // round k-1 result term
            cu = fmaxf(cup * (1.0f - rs), 0.0f);
        }
        s_p[t]  = make_float4(px, py, pz, c1 * pn);
        s_cu[t] = cu;
        if (mc == 0) {
            curout[idx] = cu;
            RSz[idx] = 0.0f; RRz[idx] = 0.0f;         // for this round's passB
        }
        if (k > 0 && mc == 0) {                        // waves 0,1 fully inside t<128
#pragma unroll
            for (int o = 32; o > 0; o >>= 1) contrib += __shfl_down(contrib, o, 64);
            if ((t & 63) == 0) s_red[t >> 6] = contrib;
        }
    }

    // thread-held columns (labels), prescaled by c1
    int m0 = mc * CHUNK + t;
    float gx[CPT], gy[CPT], gz[CPT], am[CPT], Sa[CPT], Ta[CPT];
    float n2c1 = -2.0f * c1;
#pragma unroll
    for (int c = 0; c < CPT; c++) {
        int m = m0 + c * TPB;
        const float* l = labels + (size_t)(base + m) * 3;
        float lx = l[0], ly = l[1], lz = l[2];
        gx[c] = n2c1 * lx; gy[c] = n2c1 * ly; gz[c] = n2c1 * lz;
        am[c] = c1 * (lx * lx + ly * ly + lz * lz);
        Sa[c] = 0.0f; Ta[c] = 0.0f;
    }
    __syncthreads();
    if (k > 0 && mc == 0 && t == 0) atomicAdd(out, s_red[0] + s_red[1]);

#pragma unroll 8
    for (int j = 0; j < TILE; j++) {
        float4 P = s_p[j]; float cu = s_cu[j];
#pragma unroll
        for (int c = 0; c < CPT; c++) {
            float arg = fmaf(P.x, gx[c], fmaf(P.y, gy[c], fmaf(P.z, gz[c], P.w + am[c])));
            float e = fast_exp2(arg);
            Sa[c] += e;
            Ta[c] = fmaf(e, cu, Ta[c]);
        }
    }
#pragma unroll
    for (int c = 0; c < CPT; c++) {
        int idx = base + m0 + c * TPB;
        atomicAdd(&Sacc[idx], Sa[c]);
        atomicAdd(&Tacc[idx], Ta[c]);
    }
}

// passB (fused with combA):
//   prologue: per staged column m: cc = cost*bw/D1 (from S,T,cost); nc==0 blocks
//             write cost_{k+1}, zero S/T[(k+1)&1] for next round's passA.
//   main:     RS[n] += sum_m e*cc; RR[n] += sum_m e*cc*pw (via (sum w*arg)/c1).
//   last round (ef=0): e=1, accumulate RR directly with true pw; RS not needed.
__global__ __launch_bounds__(TPB, 4) void passB(
    const float* __restrict__ preds, const float* __restrict__ labels,
    const float* __restrict__ Sread, const float* __restrict__ Tread,
    const float* __restrict__ costprev, float* __restrict__ costout,
    float* __restrict__ Sz, float* __restrict__ Tz,
    float* __restrict__ RSacc, float* __restrict__ RRacc,
    float c1, float invc1, int k, int last)
{
    __shared__ float4 s_l[TILE];
    __shared__ float  s_cc[TILE];
    int blk = blockIdx.x;
    int split = blk & 15, nc = (blk >> 4) & 1, b = blk >> 5;
    int t = threadIdx.x;
    int base = b * NN;

    if (t < TILE) {
        int idx = base + split * TILE + t;
        const float* l = labels + (size_t)idx * 3;
        float lx = l[0], ly = l[1], lz = l[2];
        float lm2 = lx * lx + ly * ly + lz * lz;
        float S = Sread[idx], T = Tread[idx];
        float cost = (k == 0) ? 1.0f : costprev[idx];
        float D1 = fmaf(cost, S, EPSF);
        float S2 = cost * T / D1;
        float bw = fminf(cost / (S2 + EPSF), 1.0f);
        float cc = cost * bw / D1;
        if (nc == 0) {
            costout[idx] = fmaxf(fmaf(-S2, bw, cost), 0.0f);
            Sz[idx] = 0.0f; Tz[idx] = 0.0f;            // for next round's passA
        }
        if (last) s_l[t] = make_float4(lx, ly, lz, lm2);
        else      s_l[t] = make_float4(-2.0f * c1 * lx, -2.0f * c1 * ly,
                                       -2.0f * c1 * lz, c1 * lm2);
        s_cc[t] = cc;
    }

    int n0 = nc * CHUNK + t;
    float px[CPT], py[CPT], pz[CPT], qq[CPT], RSa[CPT], RRa[CPT];
#pragma unroll
    for (int c = 0; c < CPT; c++) {
        int n = n0 + c * TPB;
        const float* p = preds + (size_t)(base + n) * 3;
        px[c] = p[0]; py[c] = p[1]; pz[c] = p[2];
        float pn = px[c] * px[c] + py[c] * py[c] + pz[c] * pz[c];
        qq[c] = last ? pn : c1 * pn;
        RSa[c] = 0.0f; RRa[c] = 0.0f;
    }
    __syncthreads();

    if (!last) {
#pragma unroll 8
        for (int j = 0; j < TILE; j++) {
            float4 L = s_l[j]; float ccj = s_cc[j];
#pragma unroll
            for (int c = 0; c < CPT; c++) {
                float arg = fmaf(px[c], L.x, fmaf(py[c], L.y, fmaf(pz[c], L.z, qq[c] + L.w)));
                float e = fast_exp2(arg);
                float w = e * ccj;
                RSa[c] += w;
                RRa[c] = fmaf(w, arg, RRa[c]);         // sum w*arg; *1/c1 at end
            }
        }
#pragma unroll
        for (int c = 0; c < CPT; c++) {
            int idx = base + n0 + c * TPB;
            atomicAdd(&RSacc[idx], RSa[c]);
            atomicAdd(&RRacc[idx], RRa[c] * invc1);
        }
    } else {
#pragma unroll 8
        for (int j = 0; j < TILE; j++) {
            float4 L = s_l[j]; float ccj = s_cc[j];
#pragma unroll
            for (int c = 0; c < CPT; c++) {
                float dot = fmaf(px[c], L.x, fmaf(py[c], L.y, pz[c] * L.z));
                float pw  = fmaf(-2.0f, dot, qq[c] + L.w);
                RRa[c] = fmaf(ccj, pw, RRa[c]);        // e=1, w=cc
            }
        }
#pragma unroll
        for (int c = 0; c < CPT; c++) {
            int idx = base + n0 + c * TPB;
            atomicAdd(&RRacc[idx], RRa[c]);
        }
    }
}

// round-9 result term: out += sum_n cur_9[n] * RR_9[n]
__global__ void finalK(const float* __restrict__ cur, const float* __restrict__ RR,
                       float* __restrict__ out)
{
    int t = threadIdx.x;
    int i = blockIdx.x * TPB + t;
    float contrib = cur[i] * RR[i];
#pragma unroll
    for (int o = 32; o > 0; o >>= 1) contrib += __shfl_down(contrib, o, 64);
    __shared__ float s_red[TPB / 64];
    if ((t & 63) == 0) s_red[t >> 6] = contrib;
    __syncthreads();
    if (t == 0) {
        float s = 0.0f;
#pragma unroll
        for (int w = 0; w < TPB / 64; w++) s += s_red[w];
        atomicAdd(out, s);
    }
}

extern "C" void kernel_launch(void* const* d_in, const int* in_sizes, int n_in,
                              void* d_out, int out_size, void* d_ws, size_t ws_size,
                              hipStream_t stream) {
    const float* preds  = (const float*)d_in[0];
    const float* labels = (const float*)d_in[1];
    float* out = (float*)d_out;
    float* ws  = (float*)d_ws;

    // layout: S0 T0 S1 T1 RS0 RR0 RS1 RR1 cur0 cur1 cost0 cost1  (12*BN floats = 1.5 MB)
    float* S[2]     = {ws + 0 * BN, ws + 2 * BN};
    float* T[2]     = {ws + 1 * BN, ws + 3 * BN};
    float* RS[2]    = {ws + 4 * BN, ws + 6 * BN};
    float* RR[2]    = {ws + 5 * BN, ws + 7 * BN};
    float* curb[2]  = {ws + 8 * BN, ws + 9 * BN};
    float* costb[2] = {ws + 10 * BN, ws + 11 * BN};

    hipMemsetAsync(d_out, 0, sizeof(float), stream);
    hipMemsetAsync(ws, 0, (size_t)2 * BN * sizeof(float), stream);  // S[0], T[0]

    static const float efs[10] = {-16384.0f, -4096.0f, -1024.0f, -256.0f, -64.0f,
                                  -16.0f, -4.0f, -1.0f, -0.25f, 0.0f};
    const float log2e = 1.44269504088896f;
    for (int k = 0; k < 10; k++) {
        float c1 = efs[k] * log2e;
        float invc1 = (efs[k] != 0.0f) ? 1.0f / c1 : 0.0f;
        int pk = k & 1, pp = (k + 1) & 1;   // pp == (k-1)&1 for k>=1
        passA<<<512, TPB, 0, stream>>>(preds, labels,
            curb[pp], curb[pk],     // cur_{k-1} -> cur_k
            RS[pp], RR[pp],         // prev round's row sums
            RS[pk], RR[pk],         // zero for this round's passB
            S[pk], T[pk],           // accumulate this round's col sums
            out, c1, k);
        passB<<<512, TPB, 0, stream>>>(preds, labels,
            S[pk], T[pk],
            costb[pk], costb[pp],   // cost_k -> cost_{k+1}
            S[pp], T[pp],           // zero for next round's passA
            RS[pk], RR[pk],
            c1, invc1, k, (k == 9) ? 1 : 0);
    }
    finalK<<<BN / TPB, TPB, 0, stream>>>(curb[1], RR[1], out);
}